// Round 1
// baseline (14843.863 us; speedup 1.0000x reference)
//
#include <hip/hip_runtime.h>
#include <hip/hip_bf16.h>
#include <hip/hip_cooperative_groups.h>

namespace cg = cooperative_groups;

typedef __bf16 bf16x8 __attribute__((ext_vector_type(8)));
typedef __bf16 bf16x4 __attribute__((ext_vector_type(4)));
typedef float  f32x4  __attribute__((ext_vector_type(4)));

#define DI __device__ __forceinline__

DI float ex2f_(float x){ return __builtin_amdgcn_exp2f(x); }
DI float rcpf_(float x){ return __builtin_amdgcn_rcpf(x); }

// ---------------------------------------------------------------------------
// Prologue kernels
// ---------------------------------------------------------------------------

__global__ void f32_to_bf16_k(const float* __restrict__ src, __bf16* __restrict__ dst, int n4){
  int i = blockIdx.x*256 + threadIdx.x;
  if (i >= n4) return;
  float4 v = reinterpret_cast<const float4*>(src)[i];
  bf16x4 o; o[0]=(__bf16)v.x; o[1]=(__bf16)v.y; o[2]=(__bf16)v.z; o[3]=(__bf16)v.w;
  reinterpret_cast<bf16x4*>(dst)[i] = o;
}

// emb_sbe[s][b][e] = (s==0) ? 0 : embed[labels[b][s-1]][e]   (bf16, [S][B][E])
__global__ void emb_gather_k(const float* __restrict__ embed, const int* __restrict__ labels,
                             __bf16* __restrict__ out){
  int i = blockIdx.x*256 + threadIdx.x;
  if (i >= 100*32*80) return;
  int e8 = (i % 80)*8;
  int g  = i / 80;              // g = s*32 + b
  int b  = g & 31, s = g >> 5;
  bf16x8 o;
  if (s == 0){
    #pragma unroll
    for (int u=0;u<8;u++) o[u] = (__bf16)0.f;
  } else {
    int lbl = labels[b*100 + (s-1)];
    const float* pe = embed + (size_t)lbl*640 + e8;
    #pragma unroll
    for (int u=0;u<8;u++) o[u] = (__bf16)pe[u];
  }
  *reinterpret_cast<bf16x8*>(out + (size_t)g*640 + e8) = o;
}

// inv_fert[b,t] = sigmoid(dot(enc[b,t,:], W_fert))   one wave per row
__global__ __launch_bounds__(256) void fert_k(const float* __restrict__ enc,
                       const float* __restrict__ Wf, float* __restrict__ inv_fert){
  int row  = blockIdx.x*4 + (threadIdx.x>>6);
  int lane = threadIdx.x & 63;
  const float* pr = enc + (size_t)row*512 + lane*8;
  const float* pw = Wf + lane*8;
  float4 a0 = reinterpret_cast<const float4*>(pr)[0];
  float4 a1 = reinterpret_cast<const float4*>(pr)[1];
  float4 w0 = reinterpret_cast<const float4*>(pw)[0];
  float4 w1 = reinterpret_cast<const float4*>(pw)[1];
  float acc = a0.x*w0.x + a0.y*w0.y + a0.z*w0.z + a0.w*w0.w
            + a1.x*w1.x + a1.y*w1.y + a1.z*w1.z + a1.w*w1.w;
  #pragma unroll
  for (int off=1; off<64; off<<=1) acc += __shfl_xor(acc, off, 64);
  if (lane == 0) inv_fert[row] = 1.f/(1.f + expf(-acc));
}

__global__ void init_k(float* h, float* c, __bf16* hb, float* ctx_un, float* accum,
                       float* expe, float* sumb){
  int i = blockIdx.x*256 + threadIdx.x;
  if (i < 32768){ h[i]=0.f; c[i]=0.f; hb[i]=(__bf16)0.f; }
  if (i < 16384) ctx_un[i]=0.f;
  if (i < 32000) accum[i]=0.f;
  if (i < 64000) expe[i]=0.f;
  if (i < 64)    sumb[i]=1.f;
}

// ---------------------------------------------------------------------------
// Generic bf16 MFMA GEMM:  C[m,n] = sum_k A[m,k]*B[n,k]  (B given row-major [N,K])
// MODE 0: out bf16 (+bias)                 -> enc_ctx
// MODE 1: 3-piece A (1024|640|512), +b_ro, fused pairwise maxout -> Y bf16 [M,512]
// MODE 2: out f32 (+bias), row-permuted (m=s*32+b -> r=b*100+s)  -> logits
// ---------------------------------------------------------------------------
template<int MODE>
__global__ __launch_bounds__(256) void gemm_bt(const __bf16* __restrict__ A0,
        const __bf16* __restrict__ A1, const __bf16* __restrict__ A2,
        const __bf16* __restrict__ Bw, const float* __restrict__ bias,
        float* __restrict__ outF, __bf16* __restrict__ outB, int M, int N, int K){
  __shared__ __bf16 lA[64][40];   // +8 pad -> 2-way-free LDS reads
  __shared__ __bf16 lB[64][40];
  const int m0 = blockIdx.x*64, n0 = blockIdx.y*64;
  const int tid = threadIdx.x;
  const int wave = tid>>6, lane = tid&63;
  const int wm = wave>>1, wn = wave&1;
  const int srow = tid>>2, sc8 = (tid&3)*8;
  f32x4 acc[2][2];
  #pragma unroll
  for (int a=0;a<2;a++)
    #pragma unroll
    for (int b2=0;b2<2;b2++){ acc[a][b2][0]=0.f; acc[a][b2][1]=0.f; acc[a][b2][2]=0.f; acc[a][b2][3]=0.f; }

  for (int k0 = 0; k0 < K; k0 += 32){
    const int kk = k0 + sc8;
    bf16x8 av, bv;
    if (MODE == 1){
      const int m = m0 + srow;
      if (kk < 1024)      av = *reinterpret_cast<const bf16x8*>(A0 + (size_t)m*1024 + kk);
      else if (kk < 1664) av = *reinterpret_cast<const bf16x8*>(A1 + (size_t)m*640 + (kk-1024));
      else                av = *reinterpret_cast<const bf16x8*>(A2 + (size_t)m*512 + (kk-1664));
    } else {
      av = *reinterpret_cast<const bf16x8*>(A0 + (size_t)(m0+srow)*K + kk);
    }
    bv = *reinterpret_cast<const bf16x8*>(Bw + (size_t)(n0+srow)*K + kk);
    __syncthreads();
    *reinterpret_cast<bf16x8*>(&lA[srow][sc8]) = av;
    *reinterpret_cast<bf16x8*>(&lB[srow][sc8]) = bv;
    __syncthreads();
    #pragma unroll
    for (int mt=0;mt<2;mt++){
      bf16x8 af = *reinterpret_cast<const bf16x8*>(&lA[wm*32+mt*16+(lane&15)][(lane>>4)*8]);
      #pragma unroll
      for (int nt=0;nt<2;nt++){
        bf16x8 bf = *reinterpret_cast<const bf16x8*>(&lB[wn*32+nt*16+(lane&15)][(lane>>4)*8]);
        acc[mt][nt] = __builtin_amdgcn_mfma_f32_16x16x32_bf16(af, bf, acc[mt][nt], 0,0,0);
      }
    }
  }
  #pragma unroll
  for (int mt=0;mt<2;mt++){
    #pragma unroll
    for (int nt=0;nt<2;nt++){
      #pragma unroll
      for (int r=0;r<4;r++){
        const int m = m0 + wm*32 + mt*16 + (lane>>4)*4 + r;
        const int n = n0 + wn*32 + nt*16 + (lane&15);
        float v = acc[mt][nt][r] + bias[n];
        if (MODE == 0){
          outB[(size_t)m*N + n] = (__bf16)v;
        } else if (MODE == 1){
          float vo = fmaxf(v, __shfl_xor(v, 1, 64));
          if ((lane & 1) == 0) outB[(size_t)m*512 + (n>>1)] = (__bf16)vo;
        } else {
          const int rr = (m & 31)*100 + (m >> 5);
          outF[(size_t)rr*N + n] = v;
        }
      }
    }
  }
}

// ---------------------------------------------------------------------------
// Persistent cooperative decoder: 100 steps x {A: gates+LSTM | S: s_t | B: attention}
// ---------------------------------------------------------------------------
struct DecArgs {
  const float* b_ih; const float* b_hh;
  const float* v_att; const float* W_fb;
  const int* seqlen;
  const float* inv_fert;
  const __bf16* emb_sbe;
  const __bf16* W_ih_b; const __bf16* W_hh_b; const __bf16* W_s_b;
  const __bf16* enc_ctx; const __bf16* enc_b16;
  float* h_st; float* c_st; __bf16* h_b16;
  float* s_t; float* ctx_un; float* sum_buf;   // sum_buf[2][32]
  float* accum; float* expe;                   // expe[2][32*1000]
  __bf16* s_stk; __bf16* ctx_stk;
};

__global__ __launch_bounds__(512, 1) void decoder_kernel(DecArgs g){
  cg::grid_group grid = cg::this_grid();
  const int blk = blockIdx.x, tid = threadIdx.x;
  const int wave = tid>>6, lane = tid&63;
  __shared__ float red[8][2][16][16];
  __shared__ float gbuf[2][16][16];
  __shared__ float sh_expe[128];

  for (int s = 0; s < 100; ++s){
    const int p = s & 1, pp = 1 - p;

    // ---- Phase A: gates = [emb_t | ctx_un/sum | h] @ [W_ih|W_hh]^T + biases; LSTM; zoneout
    {
      const int j0 = blk*4;                       // this block: j in [j0,j0+4), all 4 gates
      const int c = lane & 15, kg = lane >> 4;
      const int n = ((c>>2)<<10) + j0 + (c&3);    // gate row
      const int brow0 = c, brow1 = c + 16;        // batch rows for A-frags
      const float inv0 = 1.f/g.sum_buf[pp*32 + brow0];
      const float inv1 = 1.f/g.sum_buf[pp*32 + brow1];
      const int s0   = (wave<4) ? wave*9 : 36 + (wave-4)*8;   // K split: 68 steps over 8 waves
      const int scnt = (wave<4) ? 9 : 8;
      f32x4 acc0, acc1;
      acc0[0]=acc0[1]=acc0[2]=acc0[3]=0.f;
      acc1[0]=acc1[1]=acc1[2]=acc1[3]=0.f;
      const __bf16* embS = g.emb_sbe + (size_t)s*32*640;
      for (int ks = s0; ks < s0 + scnt; ++ks){
        const int kk = ks*32 + kg*8;
        bf16x8 bfrag = (kk < 1152)
          ? *reinterpret_cast<const bf16x8*>(g.W_ih_b + (size_t)n*1152 + kk)
          : *reinterpret_cast<const bf16x8*>(g.W_hh_b + (size_t)n*1024 + (kk-1152));
        bf16x8 a0, a1;
        if (kk < 640){
          a0 = *reinterpret_cast<const bf16x8*>(embS + (size_t)brow0*640 + kk);
          a1 = *reinterpret_cast<const bf16x8*>(embS + (size_t)brow1*640 + kk);
        } else if (kk < 1152){
          const float* c0 = g.ctx_un + brow0*512 + (kk-640);
          const float* c1 = g.ctx_un + brow1*512 + (kk-640);
          #pragma unroll
          for (int u=0;u<8;u++){ a0[u]=(__bf16)(c0[u]*inv0); a1[u]=(__bf16)(c1[u]*inv1); }
        } else {
          a0 = *reinterpret_cast<const bf16x8*>(g.h_b16 + brow0*1024 + (kk-1152));
          a1 = *reinterpret_cast<const bf16x8*>(g.h_b16 + brow1*1024 + (kk-1152));
        }
        acc0 = __builtin_amdgcn_mfma_f32_16x16x32_bf16(a0, bfrag, acc0, 0,0,0);
        acc1 = __builtin_amdgcn_mfma_f32_16x16x32_bf16(a1, bfrag, acc1, 0,0,0);
      }
      #pragma unroll
      for (int r=0;r<4;r++){
        red[wave][0][kg*4+r][c] = acc0[r];
        red[wave][1][kg*4+r][c] = acc1[r];
      }
      __syncthreads();
      {
        const int mt = tid>>8, row = (tid>>4)&15, col = tid&15;
        float v = 0.f;
        #pragma unroll
        for (int w=0;w<8;w++) v += red[w][mt][row][col];
        const int n2 = ((col>>2)<<10) + j0 + (col&3);
        v += g.b_ih[n2] + g.b_hh[n2];
        gbuf[mt][row][col] = v;
      }
      __syncthreads();
      if ((tid & 15) < 4){
        const int mt = tid>>8, row=(tid>>4)&15, jj = tid&3;
        const int b = mt*16 + row, j = j0 + jj;
        const float gi = gbuf[mt][row][jj];
        const float gf = gbuf[mt][row][4+jj];
        const float gg = gbuf[mt][row][8+jj];
        const float go = gbuf[mt][row][12+jj];
        const float c_old = g.c_st[b*1024+j];
        const float h_old = g.h_st[b*1024+j];
        const float si = 1.f/(1.f+expf(-gi));
        const float sf = 1.f/(1.f+expf(-gf));
        const float so = 1.f/(1.f+expf(-go));
        const float cn = sf*c_old + si*tanhf(gg);
        const float hn = so*tanhf(cn);
        const float hz = 0.05f*h_old + 0.95f*hn;   // zoneout h
        const float cz = 0.15f*c_old + 0.85f*cn;   // zoneout c
        g.c_st[b*1024+j] = cz;
        g.h_st[b*1024+j] = hz;
        const __bf16 hb = (__bf16)hz;
        g.h_b16[b*1024+j] = hb;
        g.s_stk[((size_t)s*32+b)*1024 + j] = hb;
      }
    }
    grid.sync();

    // ---- Phase S: s_t = h @ W_s^T (blocks 0-63); save ctx_stk[s-1], zero ctx_un/sum (64-96)
    if (blk < 64){
      const int n0 = blk*16;
      const int c = lane & 15, kg = lane >> 4;
      f32x4 acc0, acc1;
      acc0[0]=acc0[1]=acc0[2]=acc0[3]=0.f;
      acc1[0]=acc1[1]=acc1[2]=acc1[3]=0.f;
      #pragma unroll
      for (int i=0;i<4;i++){
        const int kk = (wave*4+i)*32 + kg*8;
        bf16x8 bfrag = *reinterpret_cast<const bf16x8*>(g.W_s_b + (size_t)(n0+c)*1024 + kk);
        bf16x8 a0 = *reinterpret_cast<const bf16x8*>(g.h_b16 + c*1024 + kk);
        bf16x8 a1 = *reinterpret_cast<const bf16x8*>(g.h_b16 + (c+16)*1024 + kk);
        acc0 = __builtin_amdgcn_mfma_f32_16x16x32_bf16(a0, bfrag, acc0, 0,0,0);
        acc1 = __builtin_amdgcn_mfma_f32_16x16x32_bf16(a1, bfrag, acc1, 0,0,0);
      }
      #pragma unroll
      for (int r=0;r<4;r++){
        red[wave][0][kg*4+r][c] = acc0[r];
        red[wave][1][kg*4+r][c] = acc1[r];
      }
      __syncthreads();
      const int mt = tid>>8, row=(tid>>4)&15, col = tid&15;
      float v = 0.f;
      #pragma unroll
      for (int w=0;w<8;w++) v += red[w][mt][row][col];
      g.s_t[(mt*16+row)*1024 + n0 + col] = v;
    } else if (blk < 96){
      const int b = blk - 64;
      if (s > 0){
        const float invp = 1.f/g.sum_buf[pp*32 + b];
        g.ctx_stk[((size_t)(s-1)*32 + b)*512 + tid] = (__bf16)(g.ctx_un[b*512+tid]*invp);
      }
      g.ctx_un[b*512 + tid] = 0.f;
    } else if (blk == 96){
      if (tid < 32) g.sum_buf[p*32 + tid] = 0.f;
    }
    grid.sync();

    // ---- Phase B: accum update, energies (tanh), exp (no-max softmax), partial ctx
    {
      const int b = blk >> 3, tc = blk & 7;
      const int t_base = tc*125;
      const int len_b = g.seqlen[b];
      const float invp = 1.f/g.sum_buf[pp*32 + b];
      const float gam = 0.5f*invp;
      float sv[16], v2[16], wf[16];
      float vbase = 0.f;
      #pragma unroll
      for (int half=0; half<2; ++half){
        const int a0i = half*512 + lane*8;
        const float4* sp = reinterpret_cast<const float4*>(g.s_t + b*1024 + a0i);
        const float4* vp = reinterpret_cast<const float4*>(g.v_att + a0i);
        const float4* fp = reinterpret_cast<const float4*>(g.W_fb + a0i);
        const float4 sA = sp[0], sB = sp[1];
        const float4 vA = vp[0], vB = vp[1];
        const float4 fA = fp[0], fB = fp[1];
        sv[half*8+0]=sA.x; sv[half*8+1]=sA.y; sv[half*8+2]=sA.z; sv[half*8+3]=sA.w;
        sv[half*8+4]=sB.x; sv[half*8+5]=sB.y; sv[half*8+6]=sB.z; sv[half*8+7]=sB.w;
        wf[half*8+0]=fA.x; wf[half*8+1]=fA.y; wf[half*8+2]=fA.z; wf[half*8+3]=fA.w;
        wf[half*8+4]=fB.x; wf[half*8+5]=fB.y; wf[half*8+6]=fB.z; wf[half*8+7]=fB.w;
        v2[half*8+0]=-2.f*vA.x; v2[half*8+1]=-2.f*vA.y; v2[half*8+2]=-2.f*vA.z; v2[half*8+3]=-2.f*vA.w;
        v2[half*8+4]=-2.f*vB.x; v2[half*8+5]=-2.f*vB.y; v2[half*8+6]=-2.f*vB.z; v2[half*8+7]=-2.f*vB.w;
        vbase += vA.x+vA.y+vA.z+vA.w+vB.x+vB.y+vB.z+vB.w;
      }
      float wsum = 0.f;
      for (int t = t_base + wave; t < t_base + 125; t += 8){
        const int idx = b*1000 + t;
        const float ac = fmaf(g.expe[pp*32000 + idx]*g.inv_fert[idx], gam, g.accum[idx]);
        if (lane == 0) g.accum[idx] = ac;
        float px = 0.f;
        if (t < len_b){
          float e = vbase;    // sum_a v[a] collected; per-elem contributes v2[a]*rcp term
          #pragma unroll
          for (int half=0; half<2; ++half){
            const bf16x8 ec = *reinterpret_cast<const bf16x8*>(
                g.enc_ctx + (size_t)idx*1024 + half*512 + lane*8);
            #pragma unroll
            for (int u=0;u<8;u++){
              const int r2 = half*8 + u;
              const float z = fmaf(ac, wf[r2], sv[r2] + (float)ec[u]);
              const float exz = ex2f_(z * 2.885390082f);        // e^(2z)
              const float rc = rcpf_(exz + 1.f);
              e = fmaf(v2[r2], rc, e);                          // += v*(1-2/(e^2z+1))
            }
          }
          #pragma unroll
          for (int off=1; off<64; off<<=1) e += __shfl_xor(e, off, 64);
          px = ex2f_(e * 1.44269504f);                          // exp(e), no-max softmax
        }
        if (lane == 0){
          g.expe[p*32000 + idx] = px;
          sh_expe[t - t_base] = px;
        }
        wsum += px;
      }
      if (lane == 0) atomicAdd(&g.sum_buf[p*32 + b], wsum);
      __syncthreads();
      // partial unnormalized ctx for this block's t-chunk
      const int tt = tid >> 8, d0 = (tid & 255)*2;
      float c0 = 0.f, c1 = 0.f;
      for (int t = t_base + tt; t < t_base + 125; t += 2){
        const float w = sh_expe[t - t_base];
        if (w != 0.f){
          const __bf16* ep = g.enc_b16 + ((size_t)(b*1000 + t)*512 + d0);
          c0 = fmaf(w, (float)ep[0], c0);
          c1 = fmaf(w, (float)ep[1], c1);
        }
      }
      atomicAdd(&g.ctx_un[b*512 + d0], c0);
      atomicAdd(&g.ctx_un[b*512 + d0 + 1], c1);
    }
    grid.sync();
  }

  // final ctx_stk[99]
  if (blk >= 64 && blk < 96){
    const int b = blk - 64;
    const float invp = 1.f/g.sum_buf[32 + b];   // step 99 wrote parity 1
    g.ctx_stk[((size_t)99*32 + b)*512 + tid] = (__bf16)(g.ctx_un[b*512 + tid]*invp);
  }
}

// ---------------------------------------------------------------------------
extern "C" void kernel_launch(void* const* d_in, const int* in_sizes, int n_in,
                              void* d_out, int out_size, void* d_ws, size_t ws_size,
                              hipStream_t stream){
  (void)in_sizes; (void)n_in; (void)out_size; (void)ws_size;
  const float* enc    = (const float*)d_in[0];
  const int*   labels = (const int*)  d_in[1];
  const int*   seqlen = (const int*)  d_in[2];
  const float* embed  = (const float*)d_in[3];
  const float* W_ih   = (const float*)d_in[4];
  const float* W_hh   = (const float*)d_in[5];
  const float* b_ih   = (const float*)d_in[6];
  const float* b_hh   = (const float*)d_in[7];
  const float* W_s    = (const float*)d_in[8];
  const float* W_enc  = (const float*)d_in[9];
  const float* b_enc  = (const float*)d_in[10];
  const float* v_att  = (const float*)d_in[11];
  const float* W_fert = (const float*)d_in[12];
  const float* W_fb   = (const float*)d_in[13];
  const float* W_ro   = (const float*)d_in[14];
  const float* b_ro   = (const float*)d_in[15];
  const float* W_out  = (const float*)d_in[16];
  const float* b_out  = (const float*)d_in[17];
  float* out = (float*)d_out;

  char* ws = (char*)d_ws;
  size_t off = 0;
  auto alloc = [&](size_t bytes)->char*{
    char* p = ws + off;
    off = (off + bytes + 255) & ~(size_t)255;
    return p;
  };
  __bf16* enc_b16 = (__bf16*)alloc(32000ull*512*2);
  __bf16* enc_ctx = (__bf16*)alloc(32000ull*1024*2);
  __bf16* W_ih_b  = (__bf16*)alloc(4096ull*1152*2);
  __bf16* W_hh_b  = (__bf16*)alloc(4096ull*1024*2);
  __bf16* W_s_b   = (__bf16*)alloc(1024ull*1024*2);
  __bf16* W_enc_b = (__bf16*)alloc(1024ull*512*2);
  __bf16* W_ro_b  = (__bf16*)alloc(1024ull*2176*2);
  __bf16* W_out_b = (__bf16*)alloc(10240ull*512*2);
  __bf16* emb_sbe = (__bf16*)alloc(3200ull*640*2);
  float*  ifert   = (float*)alloc(32000ull*4);
  __bf16* s_stk   = (__bf16*)alloc(3200ull*1024*2);
  __bf16* ctx_stk = (__bf16*)alloc(3200ull*512*2);
  float*  h_st    = (float*)alloc(32768ull*4);
  float*  c_st    = (float*)alloc(32768ull*4);
  __bf16* h_b16   = (__bf16*)alloc(32768ull*2);
  float*  s_t     = (float*)alloc(32768ull*4);
  float*  ctx_un  = (float*)alloc(16384ull*4);
  float*  sum_buf = (float*)alloc(256);
  float*  accum   = (float*)alloc(32000ull*4);
  float*  expe    = (float*)alloc(64000ull*4);
  __bf16* Y       = (__bf16*)alloc(3200ull*512*2);

  auto conv = [&](const float* s, __bf16* d, int n){
    int n4 = n/4;
    f32_to_bf16_k<<<(n4+255)/256, 256, 0, stream>>>(s, d, n4);
  };
  conv(enc,   enc_b16, 32000*512);
  conv(W_ih,  W_ih_b,  4096*1152);
  conv(W_hh,  W_hh_b,  4096*1024);
  conv(W_s,   W_s_b,   1024*1024);
  conv(W_enc, W_enc_b, 1024*512);
  conv(W_ro,  W_ro_b,  1024*2176);
  conv(W_out, W_out_b, 10240*512);

  emb_gather_k<<<(256000+255)/256, 256, 0, stream>>>(embed, labels, emb_sbe);
  fert_k<<<8000, 256, 0, stream>>>(enc, W_fert, ifert);
  init_k<<<250, 256, 0, stream>>>(h_st, c_st, h_b16, ctx_un, accum, expe, sum_buf);

  // enc_ctx = enc @ W_enc^T + b_enc   -> bf16 [32000,1024]
  gemm_bt<0><<<dim3(500,16), 256, 0, stream>>>(enc_b16, nullptr, nullptr, W_enc_b,
        b_enc, nullptr, enc_ctx, 32000, 1024, 512);

  DecArgs da;
  da.b_ih = b_ih; da.b_hh = b_hh; da.v_att = v_att; da.W_fb = W_fb;
  da.seqlen = seqlen; da.inv_fert = ifert;
  da.emb_sbe = emb_sbe; da.W_ih_b = W_ih_b; da.W_hh_b = W_hh_b; da.W_s_b = W_s_b;
  da.enc_ctx = enc_ctx; da.enc_b16 = enc_b16;
  da.h_st = h_st; da.c_st = c_st; da.h_b16 = h_b16;
  da.s_t = s_t; da.ctx_un = ctx_un; da.sum_buf = sum_buf;
  da.accum = accum; da.expe = expe;
  da.s_stk = s_stk; da.ctx_stk = ctx_stk;
  void* kargs[] = { &da };
  hipLaunchCooperativeKernel(reinterpret_cast<void*>(decoder_kernel),
                             dim3(256), dim3(512), kargs, 0, stream);

  // Y = maxout( [s_stk|emb|ctx_stk] @ W_ro^T + b_ro )  -> bf16 [3200,512]
  gemm_bt<1><<<dim3(50,16), 256, 0, stream>>>(s_stk, emb_sbe, ctx_stk, W_ro_b,
        b_ro, nullptr, Y, 3200, 1024, 2176);
  // logits = Y @ W_out^T + b_out  -> f32 d_out, rows permuted (s*32+b -> b*100+s)
  gemm_bt<2><<<dim3(50,160), 256, 0, stream>>>(Y, nullptr, nullptr, W_out_b,
        b_out, out, nullptr, 3200, 10240, 512);
}

// Round 4
// 9389.180 us; speedup vs baseline: 1.5810x; 1.5810x over previous
//
#include <hip/hip_runtime.h>
#include <hip/hip_bf16.h>

typedef __bf16 bf16x8 __attribute__((ext_vector_type(8)));
typedef __bf16 bf16x4 __attribute__((ext_vector_type(4)));
typedef float  f32x4  __attribute__((ext_vector_type(4)));
typedef unsigned long long u64;

#define DI __device__ __forceinline__

DI float ex2f_(float x){ return __builtin_amdgcn_exp2f(x); }
DI float rcpf_(float x){ return __builtin_amdgcn_rcpf(x); }

// Device-coherent (cross-XCD) accesses: relaxed agent-scope atomics lower to
// sc0/sc1-flagged loads/stores that bypass non-coherent caches -> no wbl2/inv.
DI u64 cload64(const void* p){
  return __hip_atomic_load((const u64*)p, __ATOMIC_RELAXED, __HIP_MEMORY_SCOPE_AGENT);
}
DI float cloadf(const float* p){
  return __hip_atomic_load(p, __ATOMIC_RELAXED, __HIP_MEMORY_SCOPE_AGENT);
}
DI void cstoreu(unsigned* p, unsigned v){
  __hip_atomic_store(p, v, __ATOMIC_RELAXED, __HIP_MEMORY_SCOPE_AGENT);
}
DI void cstoref(float* p, float v){
  __hip_atomic_store(p, v, __ATOMIC_RELAXED, __HIP_MEMORY_SCOPE_AGENT);
}

// One-shot barrier: each slot used exactly once per launch (no reset races).
DI void bar_sync(unsigned* slot, unsigned target){
  __syncthreads();
  if (threadIdx.x == 0){
    asm volatile("s_waitcnt vmcnt(0) lgkmcnt(0)" ::: "memory");
    __builtin_amdgcn_sched_barrier(0);
    __hip_atomic_fetch_add(slot, 1u, __ATOMIC_RELAXED, __HIP_MEMORY_SCOPE_AGENT);
    while (__hip_atomic_load(slot, __ATOMIC_RELAXED, __HIP_MEMORY_SCOPE_AGENT) < target){
      __builtin_amdgcn_s_sleep(2);
    }
  }
  __syncthreads();
}

// ---------------------------------------------------------------------------
// Prologue kernels
// ---------------------------------------------------------------------------

__global__ void f32_to_bf16_k(const float* __restrict__ src, __bf16* __restrict__ dst, int n4){
  int i = blockIdx.x*256 + threadIdx.x;
  if (i >= n4) return;
  float4 v = reinterpret_cast<const float4*>(src)[i];
  bf16x4 o; o[0]=(__bf16)v.x; o[1]=(__bf16)v.y; o[2]=(__bf16)v.z; o[3]=(__bf16)v.w;
  reinterpret_cast<bf16x4*>(dst)[i] = o;
}

__global__ void emb_gather_k(const float* __restrict__ embed, const int* __restrict__ labels,
                             __bf16* __restrict__ out){
  int i = blockIdx.x*256 + threadIdx.x;
  if (i >= 100*32*80) return;
  int e8 = (i % 80)*8;
  int g  = i / 80;              // g = s*32 + b
  int b  = g & 31, s = g >> 5;
  bf16x8 o;
  if (s == 0){
    #pragma unroll
    for (int u=0;u<8;u++) o[u] = (__bf16)0.f;
  } else {
    int lbl = labels[b*100 + (s-1)];
    const float* pe = embed + (size_t)lbl*640 + e8;
    #pragma unroll
    for (int u=0;u<8;u++) o[u] = (__bf16)pe[u];
  }
  *reinterpret_cast<bf16x8*>(out + (size_t)g*640 + e8) = o;
}

__global__ __launch_bounds__(256) void fert_k(const float* __restrict__ enc,
                       const float* __restrict__ Wf, float* __restrict__ inv_fert){
  int row  = blockIdx.x*4 + (threadIdx.x>>6);
  int lane = threadIdx.x & 63;
  const float* pr = enc + (size_t)row*512 + lane*8;
  const float* pw = Wf + lane*8;
  float4 a0 = reinterpret_cast<const float4*>(pr)[0];
  float4 a1 = reinterpret_cast<const float4*>(pr)[1];
  float4 w0 = reinterpret_cast<const float4*>(pw)[0];
  float4 w1 = reinterpret_cast<const float4*>(pw)[1];
  float acc = a0.x*w0.x + a0.y*w0.y + a0.z*w0.z + a0.w*w0.w
            + a1.x*w1.x + a1.y*w1.y + a1.z*w1.z + a1.w*w1.w;
  #pragma unroll
  for (int off=1; off<64; off<<=1) acc += __shfl_xor(acc, off, 64);
  if (lane == 0) inv_fert[row] = 1.f/(1.f + expf(-acc));
}

__global__ void init_k(float* h, float* c, __bf16* hb, float* ctx_un, float* accum,
                       float* expe, float* sumb, unsigned* bars){
  int i = blockIdx.x*256 + threadIdx.x;
  if (i < 32768){ h[i]=0.f; c[i]=0.f; hb[i]=(__bf16)0.f; }
  if (i < 16384) ctx_un[i]=0.f;
  if (i < 32000) accum[i]=0.f;
  if (i < 64000) expe[i]=0.f;
  if (i < 64)    sumb[i]=1.f;
  if (i < 3400)  bars[i]=0u;
}

// ---------------------------------------------------------------------------
// Generic bf16 MFMA GEMM (prologue/epilogue):  C = A @ B^T
// ---------------------------------------------------------------------------
template<int MODE>
__global__ __launch_bounds__(256) void gemm_bt(const __bf16* __restrict__ A0,
        const __bf16* __restrict__ A1, const __bf16* __restrict__ A2,
        const __bf16* __restrict__ Bw, const float* __restrict__ bias,
        float* __restrict__ outF, __bf16* __restrict__ outB, int M, int N, int K){
  __shared__ __bf16 lA[64][40];
  __shared__ __bf16 lB[64][40];
  const int m0 = blockIdx.x*64, n0 = blockIdx.y*64;
  const int tid = threadIdx.x;
  const int wave = tid>>6, lane = tid&63;
  const int wm = wave>>1, wn = wave&1;
  const int srow = tid>>2, sc8 = (tid&3)*8;
  f32x4 acc[2][2];
  #pragma unroll
  for (int a=0;a<2;a++)
    #pragma unroll
    for (int b2=0;b2<2;b2++){ acc[a][b2][0]=0.f; acc[a][b2][1]=0.f; acc[a][b2][2]=0.f; acc[a][b2][3]=0.f; }

  for (int k0 = 0; k0 < K; k0 += 32){
    const int kk = k0 + sc8;
    bf16x8 av, bv;
    if (MODE == 1){
      const int m = m0 + srow;
      if (kk < 1024)      av = *reinterpret_cast<const bf16x8*>(A0 + (size_t)m*1024 + kk);
      else if (kk < 1664) av = *reinterpret_cast<const bf16x8*>(A1 + (size_t)m*640 + (kk-1024));
      else                av = *reinterpret_cast<const bf16x8*>(A2 + (size_t)m*512 + (kk-1664));
    } else {
      av = *reinterpret_cast<const bf16x8*>(A0 + (size_t)(m0+srow)*K + kk);
    }
    bv = *reinterpret_cast<const bf16x8*>(Bw + (size_t)(n0+srow)*K + kk);
    __syncthreads();
    *reinterpret_cast<bf16x8*>(&lA[srow][sc8]) = av;
    *reinterpret_cast<bf16x8*>(&lB[srow][sc8]) = bv;
    __syncthreads();
    #pragma unroll
    for (int mt=0;mt<2;mt++){
      bf16x8 af = *reinterpret_cast<const bf16x8*>(&lA[wm*32+mt*16+(lane&15)][(lane>>4)*8]);
      #pragma unroll
      for (int nt=0;nt<2;nt++){
        bf16x8 bf = *reinterpret_cast<const bf16x8*>(&lB[wn*32+nt*16+(lane&15)][(lane>>4)*8]);
        acc[mt][nt] = __builtin_amdgcn_mfma_f32_16x16x32_bf16(af, bf, acc[mt][nt], 0,0,0);
      }
    }
  }
  #pragma unroll
  for (int mt=0;mt<2;mt++){
    #pragma unroll
    for (int nt=0;nt<2;nt++){
      #pragma unroll
      for (int r=0;r<4;r++){
        const int m = m0 + wm*32 + mt*16 + (lane>>4)*4 + r;
        const int n = n0 + wn*32 + nt*16 + (lane&15);
        float v = acc[mt][nt][r] + bias[n];
        if (MODE == 0){
          outB[(size_t)m*N + n] = (__bf16)v;
        } else if (MODE == 1){
          float vo = fmaxf(v, __shfl_xor(v, 1, 64));
          if ((lane & 1) == 0) outB[(size_t)m*512 + (n>>1)] = (__bf16)vo;
        } else {
          const int rr = (m & 31)*100 + (m >> 5);
          outF[(size_t)rr*N + n] = v;
        }
      }
    }
  }
}

// ---------------------------------------------------------------------------
// Persistent decoder, custom relaxed-atomic barriers (no L2 wbinv per sync).
// Per step: P (gates MFMA + LSTM, j-dist) | bar1 | Q1 (s_t slice, accum, ctx
// save/zero, per-batch) | group-bar(8) | Q2 (energies, softmax, ctx) | bar2
// ---------------------------------------------------------------------------
struct DecArgs {
  const float* b_ih; const float* b_hh;
  const float* v_att; const float* W_fb;
  const int* seqlen;
  const float* inv_fert;
  const __bf16* emb_sbe;
  const __bf16* W_ih_b; const __bf16* W_hh_b; const __bf16* W_s_b;
  const __bf16* enc_ctx; const __bf16* enc_b16;
  float* h_st; float* c_st; __bf16* h_b16;
  float* s_t; float* ctx_un; float* sum_buf;   // sum_buf[2][32]
  float* accum; float* expe;                   // expe[2][32*1000]
  __bf16* s_stk; __bf16* ctx_stk;
  unsigned* bars;   // [0..99]=bar1, [100..199]=bar2, [200+s*32+b]=group
};

struct SPd {
  __bf16 hA[32][1032];      // padded rows -> conflict-free ds_read_b128
  __bf16 cxA[32][520];
  float red[8][2][16][16];
  float gbuf[32][16];
  float sums[32];           // 1/sum_prev per batch
};
struct SQd {
  __bf16 hb[1024];
  float st[1024];
  float she[128];
  float invp;
};

__global__ __launch_bounds__(512, 1) void decoder_kernel(DecArgs g){
  __shared__ __align__(16) char smem_raw[sizeof(SPd)];
  SPd& sp = *reinterpret_cast<SPd*>(smem_raw);
  SQd& sq = *reinterpret_cast<SQd*>(smem_raw);
  const int blk = blockIdx.x, tid = threadIdx.x;
  const int wave = tid>>6, lane = tid&63;
  const int bb = blk & 31, tc = blk >> 5;   // Q-phase role: batch, t-chunk

  for (int s = 0; s < 100; ++s){
    const int p = s & 1, pp = 1 - p;

    // ================= Phase P: gates + LSTM (block owns 4 j's) ============
    {
      if (tid < 32) sp.sums[tid] = 1.f / cloadf(g.sum_buf + pp*32 + tid);
      __syncthreads();
      // stage h (coherent) -> LDS.  32 rows x 1024 bf16 = 8192 u64 chunks,
      // 256 chunks/row:  row = i>>8, col4 = (i&255)*4   (r2 bug was i>>7)
      #pragma unroll
      for (int it = 0; it < 16; ++it){
        int i = tid + it*512;
        int row = i >> 8, c4 = (i & 255) * 4;
        *reinterpret_cast<u64*>(&sp.hA[row][c4]) = cload64(g.h_b16 + row*1024 + c4);
      }
      // stage ctx (coherent, normalize, cvt bf16) -> LDS
      #pragma unroll
      for (int it = 0; it < 16; ++it){
        int i = tid + it*512;
        int row = i >> 8, c2 = (i & 255) * 2;
        u64 v = cload64(g.ctx_un + row*512 + c2);
        float2 f = __builtin_bit_cast(float2, v);
        float inv = sp.sums[row];
        __bf16 b0 = (__bf16)(f.x * inv), b1 = (__bf16)(f.y * inv);
        unsigned u = (unsigned)__builtin_bit_cast(unsigned short, b0)
                   | ((unsigned)__builtin_bit_cast(unsigned short, b1) << 16);
        *reinterpret_cast<unsigned*>(&sp.cxA[row][c2]) = u;
      }
      __syncthreads();

      const int j0 = blk*4;
      const int c = lane & 15, kg = lane >> 4;
      const int n = ((c>>2)<<10) + j0 + (c&3);
      const int brow0 = c, brow1 = c + 16;
      const int s0   = (wave<4) ? wave*9 : 36 + (wave-4)*8;
      const int scnt = (wave<4) ? 9 : 8;
      f32x4 acc0, acc1;
      acc0[0]=acc0[1]=acc0[2]=acc0[3]=0.f;
      acc1[0]=acc1[1]=acc1[2]=acc1[3]=0.f;
      const __bf16* embS = g.emb_sbe + (size_t)s*32*640;
      for (int ks = s0; ks < s0 + scnt; ++ks){
        const int kk = ks*32 + kg*8;
        bf16x8 bfrag = (kk < 1152)
          ? *reinterpret_cast<const bf16x8*>(g.W_ih_b + (size_t)n*1152 + kk)
          : *reinterpret_cast<const bf16x8*>(g.W_hh_b + (size_t)n*1024 + (kk-1152));
        bf16x8 a0, a1;
        if (kk < 640){
          a0 = *reinterpret_cast<const bf16x8*>(embS + brow0*640 + kk);
          a1 = *reinterpret_cast<const bf16x8*>(embS + brow1*640 + kk);
        } else if (kk < 1152){
          a0 = *reinterpret_cast<const bf16x8*>(&sp.cxA[brow0][kk-640]);
          a1 = *reinterpret_cast<const bf16x8*>(&sp.cxA[brow1][kk-640]);
        } else {
          a0 = *reinterpret_cast<const bf16x8*>(&sp.hA[brow0][kk-1152]);
          a1 = *reinterpret_cast<const bf16x8*>(&sp.hA[brow1][kk-1152]);
        }
        acc0 = __builtin_amdgcn_mfma_f32_16x16x32_bf16(a0, bfrag, acc0, 0,0,0);
        acc1 = __builtin_amdgcn_mfma_f32_16x16x32_bf16(a1, bfrag, acc1, 0,0,0);
      }
      #pragma unroll
      for (int r=0;r<4;r++){
        sp.red[wave][0][kg*4+r][c] = acc0[r];
        sp.red[wave][1][kg*4+r][c] = acc1[r];
      }
      __syncthreads();
      {
        const int mt = tid>>8, row = (tid>>4)&15, col = tid&15;
        float v = 0.f;
        #pragma unroll
        for (int w=0;w<8;w++) v += sp.red[w][mt][row][col];
        const int n2 = ((col>>2)<<10) + j0 + (col&3);
        sp.gbuf[mt*16+row][col] = v + g.b_ih[n2] + g.b_hh[n2];
      }
      __syncthreads();
      if (tid < 64){
        const int b = tid>>1, u = tid&1;
        unsigned packed = 0;
        #pragma unroll
        for (int d=0; d<2; ++d){
          const int cb = 2*u + d;
          const int j = j0 + cb;
          const float gi = sp.gbuf[b][cb],   gf = sp.gbuf[b][4+cb];
          const float gg = sp.gbuf[b][8+cb], go = sp.gbuf[b][12+cb];
          const float c_old = g.c_st[b*1024+j], h_old = g.h_st[b*1024+j];
          const float si = 1.f/(1.f+expf(-gi));
          const float sf = 1.f/(1.f+expf(-gf));
          const float so = 1.f/(1.f+expf(-go));
          const float cn = sf*c_old + si*tanhf(gg);
          const float hn = so*tanhf(cn);
          const float hz = 0.05f*h_old + 0.95f*hn;
          const float cz = 0.15f*c_old + 0.85f*cn;
          g.c_st[b*1024+j] = cz;                    // self-block: plain
          g.h_st[b*1024+j] = hz;
          __bf16 hb = (__bf16)hz;
          packed |= ((unsigned)__builtin_bit_cast(unsigned short, hb)) << (16*d);
        }
        cstoreu(reinterpret_cast<unsigned*>(g.h_b16 + b*1024 + j0 + 2*u), packed);
        *reinterpret_cast<unsigned*>(g.s_stk + ((size_t)s*32+b)*1024 + j0 + 2*u) = packed;
      }
    }
    bar_sync(g.bars + s, 256);

    // ================= Phase Q1: s_t slice + accum + ctx save/zero =========
    {
      if (tid < 256){
        *reinterpret_cast<u64*>(&sq.hb[tid*4]) = cload64(g.h_b16 + bb*1024 + tid*4);
      }
      if (tid == 500) sq.invp = 1.f / cloadf(g.sum_buf + pp*32 + bb);
      __syncthreads();
      const float invp = sq.invp;
      {
        const int a = tc*128 + (tid>>2), kc = tid&3;
        const __bf16* wr = g.W_s_b + (size_t)a*1024 + kc*256;
        const __bf16* hr = &sq.hb[kc*256];
        float acc = 0.f;
        #pragma unroll
        for (int i=0;i<32;i++){
          bf16x8 w8 = *reinterpret_cast<const bf16x8*>(wr + i*8);
          bf16x8 h8 = *reinterpret_cast<const bf16x8*>(hr + i*8);
          #pragma unroll
          for (int u2=0;u2<8;u2++) acc = fmaf((float)w8[u2], (float)h8[u2], acc);
        }
        acc += __shfl_xor(acc, 1, 64);
        acc += __shfl_xor(acc, 2, 64);
        if (kc == 0) cstoref(g.s_t + bb*1024 + a, acc);
      }
      if (tid < 64){
        const int d = tc*64 + tid;
        if (s > 0){
          const float cv = cloadf(g.ctx_un + bb*512 + d);
          g.ctx_stk[((size_t)(s-1)*32+bb)*512 + d] = (__bf16)(cv * invp);
        }
        cstoref(g.ctx_un + bb*512 + d, 0.f);
      }
      if (tid < 125){
        const int t = tc*125 + tid, idx = bb*1000 + t;
        g.accum[idx] = fmaf(g.expe[pp*32000+idx]*g.inv_fert[idx], 0.5f*invp, g.accum[idx]);
      }
      if (tid == 501 && tc == 0) cstoref(g.sum_buf + p*32 + bb, 0.f);
    }
    bar_sync(g.bars + 200 + s*32 + bb, 8);

    // ================= Phase Q2: energies + softmax + ctx ==================
    {
      const int t_base = tc*125;
      *reinterpret_cast<u64*>(&sq.st[tid*2]) = cload64(g.s_t + bb*1024 + tid*2);
      __syncthreads();
      const int len_b = g.seqlen[bb];
      float sv[16], v2[16], wf[16];
      float vbase = 0.f;
      #pragma unroll
      for (int half=0; half<2; ++half){
        const int a0i = half*512 + lane*8;
        const float4 sA = *reinterpret_cast<const float4*>(&sq.st[a0i]);
        const float4 sB = *reinterpret_cast<const float4*>(&sq.st[a0i+4]);
        const float4 vA = *reinterpret_cast<const float4*>(g.v_att + a0i);
        const float4 vB = *reinterpret_cast<const float4*>(g.v_att + a0i + 4);
        const float4 fA = *reinterpret_cast<const float4*>(g.W_fb + a0i);
        const float4 fB = *reinterpret_cast<const float4*>(g.W_fb + a0i + 4);
        sv[half*8+0]=sA.x; sv[half*8+1]=sA.y; sv[half*8+2]=sA.z; sv[half*8+3]=sA.w;
        sv[half*8+4]=sB.x; sv[half*8+5]=sB.y; sv[half*8+6]=sB.z; sv[half*8+7]=sB.w;
        wf[half*8+0]=fA.x; wf[half*8+1]=fA.y; wf[half*8+2]=fA.z; wf[half*8+3]=fA.w;
        wf[half*8+4]=fB.x; wf[half*8+5]=fB.y; wf[half*8+6]=fB.z; wf[half*8+7]=fB.w;
        v2[half*8+0]=-2.f*vA.x; v2[half*8+1]=-2.f*vA.y; v2[half*8+2]=-2.f*vA.z; v2[half*8+3]=-2.f*vA.w;
        v2[half*8+4]=-2.f*vB.x; v2[half*8+5]=-2.f*vB.y; v2[half*8+6]=-2.f*vB.z; v2[half*8+7]=-2.f*vB.w;
        vbase += vA.x+vA.y+vA.z+vA.w+vB.x+vB.y+vB.z+vB.w;
      }
      float wsum = 0.f;
      for (int t = t_base + wave; t < t_base + 125; t += 8){
        const int idx = bb*1000 + t;
        float px = 0.f;
        if (t < len_b){
          const float ac = g.accum[idx];            // self-block: plain
          float e = vbase;
          #pragma unroll
          for (int half=0; half<2; ++half){
            const bf16x8 ec = *reinterpret_cast<const bf16x8*>(
                g.enc_ctx + (size_t)idx*1024 + half*512 + lane*8);
            #pragma unroll
            for (int u=0;u<8;u++){
              const int r2 = half*8 + u;
              const float z = fmaf(ac, wf[r2], sv[r2] + (float)ec[u]);
              const float exz = ex2f_(z * 2.885390082f);
              const float rc = rcpf_(exz + 1.f);
              e = fmaf(v2[r2], rc, e);
            }
          }
          #pragma unroll
          for (int off=1; off<64; off<<=1) e += __shfl_xor(e, off, 64);
          px = ex2f_(e * 1.44269504f);
        }
        if (lane == 0){
          g.expe[p*32000 + idx] = px;               // self-block: plain
          sq.she[t - t_base] = px;
        }
        wsum += px;
      }
      if (lane == 0) atomicAdd(g.sum_buf + p*32 + bb, wsum);
      __syncthreads();
      const int tt = tid >> 8, d0 = (tid & 255)*2;
      float c0 = 0.f, c1 = 0.f;
      for (int t = t_base + tt; t < t_base + 125; t += 2){
        const float w = sq.she[t - t_base];
        if (w != 0.f){
          const __bf16* ep = g.enc_b16 + ((size_t)(bb*1000 + t)*512 + d0);
          c0 = fmaf(w, (float)ep[0], c0);
          c1 = fmaf(w, (float)ep[1], c1);
        }
      }
      atomicAdd(g.ctx_un + bb*512 + d0, c0);
      atomicAdd(g.ctx_un + bb*512 + d0 + 1, c1);
    }
    bar_sync(g.bars + 100 + s, 256);
  }

  // final ctx_stk[99] (step 99 parity p=1)
  if (tid < 64){
    const int d = tc*64 + tid;
    const float invp = 1.f / cloadf(g.sum_buf + 32 + bb);
    const float cv = cloadf(g.ctx_un + bb*512 + d);
    g.ctx_stk[((size_t)99*32 + bb)*512 + d] = (__bf16)(cv * invp);
  }
}

// ---------------------------------------------------------------------------
extern "C" void kernel_launch(void* const* d_in, const int* in_sizes, int n_in,
                              void* d_out, int out_size, void* d_ws, size_t ws_size,
                              hipStream_t stream){
  (void)in_sizes; (void)n_in; (void)out_size; (void)ws_size;
  const float* enc    = (const float*)d_in[0];
  const int*   labels = (const int*)  d_in[1];
  const int*   seqlen = (const int*)  d_in[2];
  const float* embed  = (const float*)d_in[3];
  const float* W_ih   = (const float*)d_in[4];
  const float* W_hh   = (const float*)d_in[5];
  const float* b_ih   = (const float*)d_in[6];
  const float* b_hh   = (const float*)d_in[7];
  const float* W_s    = (const float*)d_in[8];
  const float* W_enc  = (const float*)d_in[9];
  const float* b_enc  = (const float*)d_in[10];
  const float* v_att  = (const float*)d_in[11];
  const float* W_fert = (const float*)d_in[12];
  const float* W_fb   = (const float*)d_in[13];
  const float* W_ro   = (const float*)d_in[14];
  const float* b_ro   = (const float*)d_in[15];
  const float* W_out  = (const float*)d_in[16];
  const float* b_out  = (const float*)d_in[17];
  float* out = (float*)d_out;

  char* ws = (char*)d_ws;
  size_t off = 0;
  auto alloc = [&](size_t bytes)->char*{
    char* p = ws + off;
    off = (off + bytes + 255) & ~(size_t)255;
    return p;
  };
  __bf16* enc_b16 = (__bf16*)alloc(32000ull*512*2);
  __bf16* enc_ctx = (__bf16*)alloc(32000ull*1024*2);
  __bf16* W_ih_b  = (__bf16*)alloc(4096ull*1152*2);
  __bf16* W_hh_b  = (__bf16*)alloc(4096ull*1024*2);
  __bf16* W_s_b   = (__bf16*)alloc(1024ull*1024*2);
  __bf16* W_enc_b = (__bf16*)alloc(1024ull*512*2);
  __bf16* W_ro_b  = (__bf16*)alloc(1024ull*2176*2);
  __bf16* W_out_b = (__bf16*)alloc(10240ull*512*2);
  __bf16* emb_sbe = (__bf16*)alloc(3200ull*640*2);
  float*  ifert   = (float*)alloc(32000ull*4);
  __bf16* s_stk   = (__bf16*)alloc(3200ull*1024*2);
  __bf16* ctx_stk = (__bf16*)alloc(3200ull*512*2);
  float*  h_st    = (float*)alloc(32768ull*4);
  float*  c_st    = (float*)alloc(32768ull*4);
  __bf16* h_b16   = (__bf16*)alloc(32768ull*2);
  float*  s_t     = (float*)alloc(32768ull*4);
  float*  ctx_un  = (float*)alloc(16384ull*4);
  float*  sum_buf = (float*)alloc(256);
  float*  accum   = (float*)alloc(32000ull*4);
  float*  expe    = (float*)alloc(64000ull*4);
  __bf16* Y       = (__bf16*)alloc(3200ull*512*2);
  unsigned* bars  = (unsigned*)alloc(3400ull*4);

  auto conv = [&](const float* s, __bf16* d, int n){
    int n4 = n/4;
    f32_to_bf16_k<<<(n4+255)/256, 256, 0, stream>>>(s, d, n4);
  };
  conv(enc,   enc_b16, 32000*512);
  conv(W_ih,  W_ih_b,  4096*1152);
  conv(W_hh,  W_hh_b,  4096*1024);
  conv(W_s,   W_s_b,   1024*1024);
  conv(W_enc, W_enc_b, 1024*512);
  conv(W_ro,  W_ro_b,  1024*2176);
  conv(W_out, W_out_b, 10240*512);

  emb_gather_k<<<(256000+255)/256, 256, 0, stream>>>(embed, labels, emb_sbe);
  fert_k<<<8000, 256, 0, stream>>>(enc, W_fert, ifert);
  init_k<<<250, 256, 0, stream>>>(h_st, c_st, h_b16, ctx_un, accum, expe, sum_buf, bars);

  gemm_bt<0><<<dim3(500,16), 256, 0, stream>>>(enc_b16, nullptr, nullptr, W_enc_b,
        b_enc, nullptr, enc_ctx, 32000, 1024, 512);

  DecArgs da;
  da.b_ih = b_ih; da.b_hh = b_hh; da.v_att = v_att; da.W_fb = W_fb;
  da.seqlen = seqlen; da.inv_fert = ifert;
  da.emb_sbe = emb_sbe; da.W_ih_b = W_ih_b; da.W_hh_b = W_hh_b; da.W_s_b = W_s_b;
  da.enc_ctx = enc_ctx; da.enc_b16 = enc_b16;
  da.h_st = h_st; da.c_st = c_st; da.h_b16 = h_b16;
  da.s_t = s_t; da.ctx_un = ctx_un; da.sum_buf = sum_buf;
  da.accum = accum; da.expe = expe;
  da.s_stk = s_stk; da.ctx_stk = ctx_stk;
  da.bars = bars;
  void* kargs[] = { &da };
  hipLaunchCooperativeKernel(reinterpret_cast<void*>(decoder_kernel),
                             dim3(256), dim3(512), kargs, 0, stream);

  gemm_bt<1><<<dim3(50,16), 256, 0, stream>>>(s_stk, emb_sbe, ctx_stk, W_ro_b,
        b_ro, nullptr, Y, 3200, 1024, 2176);
  gemm_bt<2><<<dim3(50,160), 256, 0, stream>>>(Y, nullptr, nullptr, W_out_b,
        b_out, out, nullptr, 3200, 10240, 512);
}

// Round 5
// 7265.704 us; speedup vs baseline: 2.0430x; 1.2923x over previous
//
#include <hip/hip_runtime.h>
#include <hip/hip_bf16.h>

typedef __bf16 bf16x8 __attribute__((ext_vector_type(8)));
typedef __bf16 bf16x4 __attribute__((ext_vector_type(4)));
typedef float  f32x4  __attribute__((ext_vector_type(4)));
typedef unsigned long long u64;

#define DI __device__ __forceinline__

DI float ex2f_(float x){ return __builtin_amdgcn_exp2f(x); }
DI float rcpf_(float x){ return __builtin_amdgcn_rcpf(x); }

// Device-coherent (cross-XCD) accesses: relaxed agent-scope atomics lower to
// sc-flagged loads/stores coherent at the device coherence point (no wbinv).
DI u64 cload64(const void* p){
  return __hip_atomic_load((const u64*)p, __ATOMIC_RELAXED, __HIP_MEMORY_SCOPE_AGENT);
}
DI float cloadf(const float* p){
  return __hip_atomic_load(p, __ATOMIC_RELAXED, __HIP_MEMORY_SCOPE_AGENT);
}
DI void cstoreu(unsigned* p, unsigned v){
  __hip_atomic_store(p, v, __ATOMIC_RELAXED, __HIP_MEMORY_SCOPE_AGENT);
}
DI void cstoref(float* p, float v){
  __hip_atomic_store(p, v, __ATOMIC_RELAXED, __HIP_MEMORY_SCOPE_AGENT);
}

// One-shot barrier, arrive-counter + release-flag (pollers don't contend with
// the RMW stream). Each slot pair used exactly once per launch.
DI void bar_sync(unsigned* cnt, unsigned* flag, unsigned target){
  __syncthreads();
  if (threadIdx.x == 0){
    asm volatile("s_waitcnt vmcnt(0) lgkmcnt(0)" ::: "memory");
    __builtin_amdgcn_sched_barrier(0);
    unsigned old = __hip_atomic_fetch_add(cnt, 1u, __ATOMIC_RELAXED, __HIP_MEMORY_SCOPE_AGENT);
    if (old == target - 1u){
      __hip_atomic_store(flag, 1u, __ATOMIC_RELAXED, __HIP_MEMORY_SCOPE_AGENT);
    } else {
      while (__hip_atomic_load(flag, __ATOMIC_RELAXED, __HIP_MEMORY_SCOPE_AGENT) == 0u){
        __builtin_amdgcn_s_sleep(2);
      }
    }
    __builtin_amdgcn_sched_barrier(0);
  }
  __syncthreads();
}

// ---------------------------------------------------------------------------
// Prologue kernels
// ---------------------------------------------------------------------------

__global__ void f32_to_bf16_k(const float* __restrict__ src, __bf16* __restrict__ dst, int n4){
  int i = blockIdx.x*256 + threadIdx.x;
  if (i >= n4) return;
  float4 v = reinterpret_cast<const float4*>(src)[i];
  bf16x4 o; o[0]=(__bf16)v.x; o[1]=(__bf16)v.y; o[2]=(__bf16)v.z; o[3]=(__bf16)v.w;
  reinterpret_cast<bf16x4*>(dst)[i] = o;
}

__global__ void emb_gather_k(const float* __restrict__ embed, const int* __restrict__ labels,
                             __bf16* __restrict__ out){
  int i = blockIdx.x*256 + threadIdx.x;
  if (i >= 100*32*80) return;
  int e8 = (i % 80)*8;
  int g  = i / 80;              // g = s*32 + b
  int b  = g & 31, s = g >> 5;
  bf16x8 o;
  if (s == 0){
    #pragma unroll
    for (int u=0;u<8;u++) o[u] = (__bf16)0.f;
  } else {
    int lbl = labels[b*100 + (s-1)];
    const float* pe = embed + (size_t)lbl*640 + e8;
    #pragma unroll
    for (int u=0;u<8;u++) o[u] = (__bf16)pe[u];
  }
  *reinterpret_cast<bf16x8*>(out + (size_t)g*640 + e8) = o;
}

__global__ __launch_bounds__(256) void fert_k(const float* __restrict__ enc,
                       const float* __restrict__ Wf, float* __restrict__ inv_fert){
  int row  = blockIdx.x*4 + (threadIdx.x>>6);
  int lane = threadIdx.x & 63;
  const float* pr = enc + (size_t)row*512 + lane*8;
  const float* pw = Wf + lane*8;
  float4 a0 = reinterpret_cast<const float4*>(pr)[0];
  float4 a1 = reinterpret_cast<const float4*>(pr)[1];
  float4 w0 = reinterpret_cast<const float4*>(pw)[0];
  float4 w1 = reinterpret_cast<const float4*>(pw)[1];
  float acc = a0.x*w0.x + a0.y*w0.y + a0.z*w0.z + a0.w*w0.w
            + a1.x*w1.x + a1.y*w1.y + a1.z*w1.z + a1.w*w1.w;
  #pragma unroll
  for (int off=1; off<64; off<<=1) acc += __shfl_xor(acc, off, 64);
  if (lane == 0) inv_fert[row] = 1.f/(1.f + expf(-acc));
}

__global__ void init_k(float* h, float* c, __bf16* hb, float* ctx_un, float* accum,
                       float* expe, float* sumb, unsigned* bars){
  int i = blockIdx.x*256 + threadIdx.x;
  if (i < 32768){ h[i]=0.f; c[i]=0.f; hb[i]=(__bf16)0.f; }
  if (i < 16384) ctx_un[i]=0.f;
  if (i < 32000) accum[i]=0.f;
  if (i < 64000) expe[i]=0.f;
  if (i < 64)    sumb[i]=1.f;
  if (i < 8192)  bars[i]=0u;
}

// ---------------------------------------------------------------------------
// Generic bf16 MFMA GEMM (prologue/epilogue):  C = A @ B^T
// ---------------------------------------------------------------------------
template<int MODE>
__global__ __launch_bounds__(256) void gemm_bt(const __bf16* __restrict__ A0,
        const __bf16* __restrict__ A1, const __bf16* __restrict__ A2,
        const __bf16* __restrict__ Bw, const float* __restrict__ bias,
        float* __restrict__ outF, __bf16* __restrict__ outB, int M, int N, int K){
  __shared__ __bf16 lA[64][40];
  __shared__ __bf16 lB[64][40];
  const int m0 = blockIdx.x*64, n0 = blockIdx.y*64;
  const int tid = threadIdx.x;
  const int wave = tid>>6, lane = tid&63;
  const int wm = wave>>1, wn = wave&1;
  const int srow = tid>>2, sc8 = (tid&3)*8;
  f32x4 acc[2][2];
  #pragma unroll
  for (int a=0;a<2;a++)
    #pragma unroll
    for (int b2=0;b2<2;b2++){ acc[a][b2][0]=0.f; acc[a][b2][1]=0.f; acc[a][b2][2]=0.f; acc[a][b2][3]=0.f; }

  for (int k0 = 0; k0 < K; k0 += 32){
    const int kk = k0 + sc8;
    bf16x8 av, bv;
    if (MODE == 1){
      const int m = m0 + srow;
      if (kk < 1024)      av = *reinterpret_cast<const bf16x8*>(A0 + (size_t)m*1024 + kk);
      else if (kk < 1664) av = *reinterpret_cast<const bf16x8*>(A1 + (size_t)m*640 + (kk-1024));
      else                av = *reinterpret_cast<const bf16x8*>(A2 + (size_t)m*512 + (kk-1664));
    } else {
      av = *reinterpret_cast<const bf16x8*>(A0 + (size_t)(m0+srow)*K + kk);
    }
    bv = *reinterpret_cast<const bf16x8*>(Bw + (size_t)(n0+srow)*K + kk);
    __syncthreads();
    *reinterpret_cast<bf16x8*>(&lA[srow][sc8]) = av;
    *reinterpret_cast<bf16x8*>(&lB[srow][sc8]) = bv;
    __syncthreads();
    #pragma unroll
    for (int mt=0;mt<2;mt++){
      bf16x8 af = *reinterpret_cast<const bf16x8*>(&lA[wm*32+mt*16+(lane&15)][(lane>>4)*8]);
      #pragma unroll
      for (int nt=0;nt<2;nt++){
        bf16x8 bf = *reinterpret_cast<const bf16x8*>(&lB[wn*32+nt*16+(lane&15)][(lane>>4)*8]);
        acc[mt][nt] = __builtin_amdgcn_mfma_f32_16x16x32_bf16(af, bf, acc[mt][nt], 0,0,0);
      }
    }
  }
  #pragma unroll
  for (int mt=0;mt<2;mt++){
    #pragma unroll
    for (int nt=0;nt<2;nt++){
      #pragma unroll
      for (int r=0;r<4;r++){
        const int m = m0 + wm*32 + mt*16 + (lane>>4)*4 + r;
        const int n = n0 + wn*32 + nt*16 + (lane&15);
        float v = acc[mt][nt][r] + bias[n];
        if (MODE == 0){
          outB[(size_t)m*N + n] = (__bf16)v;
        } else if (MODE == 1){
          float vo = fmaxf(v, __shfl_xor(v, 1, 64));
          if ((lane & 1) == 0) outB[(size_t)m*512 + (n>>1)] = (__bf16)vo;
        } else {
          const int rr = (m & 31)*100 + (m >> 5);
          outF[(size_t)rr*N + n] = v;
        }
      }
    }
  }
}

// ---------------------------------------------------------------------------
// Persistent decoder. Per step:
//   P (gates MFMA + LSTM, j-dist) | bar1 | Q1 (s_t slice, accum, ctx save/zero)
//   | group-bar(8) | Q2 (energies pipelined, softmax, vectorized ctx) | bar2
// ---------------------------------------------------------------------------
struct DecArgs {
  const float* b_ih; const float* b_hh;
  const float* v_att; const float* W_fb;
  const int* seqlen;
  const float* inv_fert;
  const __bf16* emb_sbe;
  const __bf16* W_ih_b; const __bf16* W_hh_b; const __bf16* W_s_b;
  const __bf16* enc_ctx; const __bf16* enc_b16;
  float* h_st; float* c_st; __bf16* h_b16;
  float* s_t; float* ctx_un; float* sum_buf;   // sum_buf[2][32]
  float* accum; float* expe;                   // expe[2][32*1000]
  __bf16* s_stk; __bf16* ctx_stk;
  unsigned* bars;   // counters [0..4095], flags [4096..8191]
};

struct SPd {
  __bf16 hA[32][1032];      // padded rows
  __bf16 cxA[32][520];
  float red[8][2][16][16];
  float gbuf[32][16];
  float sums[32];           // 1/sum_prev per batch
};
struct SQd {
  __bf16 hb[1024];
  float st[1024];
  float she[128];
  float invp;
  float cred[8][516];       // ctx partial sums per wave
};

__global__ __launch_bounds__(512, 1) void decoder_kernel(DecArgs g){
  __shared__ __align__(16) char smem_raw[sizeof(SPd)];
  SPd& sp = *reinterpret_cast<SPd*>(smem_raw);
  SQd& sq = *reinterpret_cast<SQd*>(smem_raw);
  const int blk = blockIdx.x, tid = threadIdx.x;
  const int wave = tid>>6, lane = tid&63;
  const int bb = blk & 31, tc = blk >> 5;   // Q-phase role: batch, t-chunk
  unsigned* bflag = g.bars + 4096;

  for (int s = 0; s < 100; ++s){
    const int p = s & 1, pp = 1 - p;

    // ================= Phase P: gates + LSTM (block owns 4 j's) ============
    {
      if (tid < 32) sp.sums[tid] = 1.f / cloadf(g.sum_buf + pp*32 + tid);
      __syncthreads();
      // stage h (coherent) -> LDS. 256 u64 chunks per row.
      #pragma unroll
      for (int it = 0; it < 16; ++it){
        int i = tid + it*512;
        int row = i >> 8, c4 = (i & 255) * 4;
        *reinterpret_cast<u64*>(&sp.hA[row][c4]) = cload64(g.h_b16 + row*1024 + c4);
      }
      // stage ctx (coherent, normalize, cvt bf16) -> LDS
      #pragma unroll
      for (int it = 0; it < 16; ++it){
        int i = tid + it*512;
        int row = i >> 8, c2 = (i & 255) * 2;
        u64 v = cload64(g.ctx_un + row*512 + c2);
        float2 f = __builtin_bit_cast(float2, v);
        float inv = sp.sums[row];
        __bf16 b0 = (__bf16)(f.x * inv), b1 = (__bf16)(f.y * inv);
        unsigned u = (unsigned)__builtin_bit_cast(unsigned short, b0)
                   | ((unsigned)__builtin_bit_cast(unsigned short, b1) << 16);
        *reinterpret_cast<unsigned*>(&sp.cxA[row][c2]) = u;
      }
      __syncthreads();

      const int j0 = blk*4;
      const int c = lane & 15, kg = lane >> 4;
      const int n = ((c>>2)<<10) + j0 + (c&3);
      const int brow0 = c, brow1 = c + 16;
      const int s0   = (wave<4) ? wave*9 : 36 + (wave-4)*8;
      const int scnt = (wave<4) ? 9 : 8;
      f32x4 acc0, acc1;
      acc0[0]=acc0[1]=acc0[2]=acc0[3]=0.f;
      acc1[0]=acc1[1]=acc1[2]=acc1[3]=0.f;
      const __bf16* embS = g.emb_sbe + (size_t)s*32*640;
      for (int ks = s0; ks < s0 + scnt; ++ks){
        const int kk = ks*32 + kg*8;
        bf16x8 bfrag = (kk < 1152)
          ? *reinterpret_cast<const bf16x8*>(g.W_ih_b + (size_t)n*1152 + kk)
          : *reinterpret_cast<const bf16x8*>(g.W_hh_b + (size_t)n*1024 + (kk-1152));
        bf16x8 a0, a1;
        if (kk < 640){
          a0 = *reinterpret_cast<const bf16x8*>(embS + brow0*640 + kk);
          a1 = *reinterpret_cast<const bf16x8*>(embS + brow1*640 + kk);
        } else if (kk < 1152){
          a0 = *reinterpret_cast<const bf16x8*>(&sp.cxA[brow0][kk-640]);
          a1 = *reinterpret_cast<const bf16x8*>(&sp.cxA[brow1][kk-640]);
        } else {
          a0 = *reinterpret_cast<const bf16x8*>(&sp.hA[brow0][kk-1152]);
          a1 = *reinterpret_cast<const bf16x8*>(&sp.hA[brow1][kk-1152]);
        }
        acc0 = __builtin_amdgcn_mfma_f32_16x16x32_bf16(a0, bfrag, acc0, 0,0,0);
        acc1 = __builtin_amdgcn_mfma_f32_16x16x32_bf16(a1, bfrag, acc1, 0,0,0);
      }
      #pragma unroll
      for (int r=0;r<4;r++){
        sp.red[wave][0][kg*4+r][c] = acc0[r];
        sp.red[wave][1][kg*4+r][c] = acc1[r];
      }
      __syncthreads();
      {
        const int mt = tid>>8, row = (tid>>4)&15, col = tid&15;
        float v = 0.f;
        #pragma unroll
        for (int w=0;w<8;w++) v += sp.red[w][mt][row][col];
        const int n2 = ((col>>2)<<10) + j0 + (col&3);
        sp.gbuf[mt*16+row][col] = v + g.b_ih[n2] + g.b_hh[n2];
      }
      __syncthreads();
      if (tid < 64){
        const int b = tid>>1, u = tid&1;
        unsigned packed = 0;
        #pragma unroll
        for (int d=0; d<2; ++d){
          const int cb = 2*u + d;
          const int j = j0 + cb;
          const float gi = sp.gbuf[b][cb],   gf = sp.gbuf[b][4+cb];
          const float gg = sp.gbuf[b][8+cb], go = sp.gbuf[b][12+cb];
          const float c_old = g.c_st[b*1024+j], h_old = g.h_st[b*1024+j];
          const float si = 1.f/(1.f+expf(-gi));
          const float sf = 1.f/(1.f+expf(-gf));
          const float so = 1.f/(1.f+expf(-go));
          const float cn = sf*c_old + si*tanhf(gg);
          const float hn = so*tanhf(cn);
          const float hz = 0.05f*h_old + 0.95f*hn;
          const float cz = 0.15f*c_old + 0.85f*cn;
          g.c_st[b*1024+j] = cz;                    // self-block: plain
          g.h_st[b*1024+j] = hz;
          __bf16 hb = (__bf16)hz;
          packed |= ((unsigned)__builtin_bit_cast(unsigned short, hb)) << (16*d);
        }
        cstoreu(reinterpret_cast<unsigned*>(g.h_b16 + b*1024 + j0 + 2*u), packed);
        *reinterpret_cast<unsigned*>(g.s_stk + ((size_t)s*32+b)*1024 + j0 + 2*u) = packed;
      }
    }
    bar_sync(g.bars + s, bflag + s, 256);

    // ================= Phase Q1: s_t slice + accum + ctx save/zero =========
    {
      if (tid < 256){
        *reinterpret_cast<u64*>(&sq.hb[tid*4]) = cload64(g.h_b16 + bb*1024 + tid*4);
      }
      if (tid == 500) sq.invp = 1.f / cloadf(g.sum_buf + pp*32 + bb);
      __syncthreads();
      const float invp = sq.invp;
      {
        const int a = tc*128 + (tid>>2), kc = tid&3;
        const __bf16* wr = g.W_s_b + (size_t)a*1024 + kc*256;
        const __bf16* hr = &sq.hb[kc*256];
        float acc = 0.f;
        #pragma unroll
        for (int i=0;i<32;i++){
          bf16x8 w8 = *reinterpret_cast<const bf16x8*>(wr + i*8);
          bf16x8 h8 = *reinterpret_cast<const bf16x8*>(hr + i*8);
          #pragma unroll
          for (int u2=0;u2<8;u2++) acc = fmaf((float)w8[u2], (float)h8[u2], acc);
        }
        acc += __shfl_xor(acc, 1, 64);
        acc += __shfl_xor(acc, 2, 64);
        if (kc == 0) cstoref(g.s_t + bb*1024 + a, acc);
      }
      if (tid < 64){
        const int d = tc*64 + tid;
        if (s > 0){
          const float cv = cloadf(g.ctx_un + bb*512 + d);
          g.ctx_stk[((size_t)(s-1)*32+bb)*512 + d] = (__bf16)(cv * invp);
        }
        cstoref(g.ctx_un + bb*512 + d, 0.f);
      }
      if (tid < 125){
        const int t = tc*125 + tid, idx = bb*1000 + t;
        g.accum[idx] = fmaf(g.expe[pp*32000+idx]*g.inv_fert[idx], 0.5f*invp, g.accum[idx]);
      }
      if (tid == 501 && tc == 0) cstoref(g.sum_buf + p*32 + bb, 0.f);
    }
    bar_sync(g.bars + 200 + s*32 + bb, bflag + 200 + s*32 + bb, 8);

    // ================= Phase Q2: energies + softmax + ctx ==================
    {
      const int t_base = tc*125;
      *reinterpret_cast<u64*>(&sq.st[tid*2]) = cload64(g.s_t + bb*1024 + tid*2);
      __syncthreads();
      const int len_b = g.seqlen[bb];
      float sv[16], v2[16], wf[16];
      float vbase = 0.f;
      #pragma unroll
      for (int half=0; half<2; ++half){
        const int a0i = half*512 + lane*8;
        const float4 sA = *reinterpret_cast<const float4*>(&sq.st[a0i]);
        const float4 sB = *reinterpret_cast<const float4*>(&sq.st[a0i+4]);
        const float4 vA = *reinterpret_cast<const float4*>(g.v_att + a0i);
        const float4 vB = *reinterpret_cast<const float4*>(g.v_att + a0i + 4);
        const float4 fA = *reinterpret_cast<const float4*>(g.W_fb + a0i);
        const float4 fB = *reinterpret_cast<const float4*>(g.W_fb + a0i + 4);
        sv[half*8+0]=sA.x; sv[half*8+1]=sA.y; sv[half*8+2]=sA.z; sv[half*8+3]=sA.w;
        sv[half*8+4]=sB.x; sv[half*8+5]=sB.y; sv[half*8+6]=sB.z; sv[half*8+7]=sB.w;
        wf[half*8+0]=fA.x; wf[half*8+1]=fA.y; wf[half*8+2]=fA.z; wf[half*8+3]=fA.w;
        wf[half*8+4]=fB.x; wf[half*8+5]=fB.y; wf[half*8+6]=fB.z; wf[half*8+7]=fB.w;
        v2[half*8+0]=-2.f*vA.x; v2[half*8+1]=-2.f*vA.y; v2[half*8+2]=-2.f*vA.z; v2[half*8+3]=-2.f*vA.w;
        v2[half*8+4]=-2.f*vB.x; v2[half*8+5]=-2.f*vB.y; v2[half*8+6]=-2.f*vB.z; v2[half*8+7]=-2.f*vB.w;
        vbase += vA.x+vA.y+vA.z+vA.w+vB.x+vB.y+vB.z+vB.w;
      }
      // energies: 2-deep prefetch pipeline over t (stride 8 per wave)
      float wsum = 0.f;
      {
        const __bf16* ebase = g.enc_ctx + ((size_t)bb*1000)*1024 + lane*8;
        const int nIter = (wave < 5) ? 16 : 15;  // t = t_base+wave+8k <= t_base+124
        int t = t_base + wave;
        bf16x8 curA = *reinterpret_cast<const bf16x8*>(ebase + (size_t)t*1024);
        bf16x8 curB = *reinterpret_cast<const bf16x8*>(ebase + (size_t)t*1024 + 512);
        for (int k = 0; k < nIter; ++k){
          const int tn = t + 8;
          bf16x8 nxtA = curA, nxtB = curB;
          if (k + 1 < nIter){
            nxtA = *reinterpret_cast<const bf16x8*>(ebase + (size_t)tn*1024);
            nxtB = *reinterpret_cast<const bf16x8*>(ebase + (size_t)tn*1024 + 512);
          }
          const int idx = bb*1000 + t;
          float px = 0.f;
          if (t < len_b){
            const float ac = g.accum[idx];            // self-block: plain
            float e = vbase;
            #pragma unroll
            for (int u=0;u<8;u++){
              const float z = fmaf(ac, wf[u], sv[u] + (float)curA[u]);
              e = fmaf(v2[u], rcpf_(ex2f_(z * 2.885390082f) + 1.f), e);
            }
            #pragma unroll
            for (int u=0;u<8;u++){
              const float z = fmaf(ac, wf[8+u], sv[8+u] + (float)curB[u]);
              e = fmaf(v2[8+u], rcpf_(ex2f_(z * 2.885390082f) + 1.f), e);
            }
            #pragma unroll
            for (int off=1; off<64; off<<=1) e += __shfl_xor(e, off, 64);
            px = ex2f_(e * 1.44269504f);
          }
          if (lane == 0){
            g.expe[p*32000 + idx] = px;               // self-block: plain
            sq.she[t - t_base] = px;
          }
          wsum += px;
          curA = nxtA; curB = nxtB;
          t = tn;
        }
      }
      if (lane == 0) atomicAdd(g.sum_buf + p*32 + bb, wsum);
      __syncthreads();
      // ctx accumulation: vectorized unguarded bf16x8 loads, LDS tt-reduce
      {
        const int d8 = (tid & 63) * 8;
        const int tt = wave;
        float cacc[8];
        #pragma unroll
        for (int u=0;u<8;u++) cacc[u] = 0.f;
        const __bf16* vb = g.enc_b16 + ((size_t)bb*1000)*512 + d8;
        const int nI2 = (tt < 5) ? 16 : 15;
        int t2 = t_base + tt;
        #pragma unroll 4
        for (int k = 0; k < nI2; ++k){
          const float w = sq.she[t2 - t_base];
          const bf16x8 ev = *reinterpret_cast<const bf16x8*>(vb + (size_t)t2*512);
          #pragma unroll
          for (int u=0;u<8;u++) cacc[u] = fmaf(w, (float)ev[u], cacc[u]);
          t2 += 8;
        }
        #pragma unroll
        for (int u=0;u<8;u++) sq.cred[tt][d8+u] = cacc[u];
        __syncthreads();
        const int d = tid & 511;
        float ssum = 0.f;
        #pragma unroll
        for (int w8=0; w8<8; ++w8) ssum += sq.cred[w8][d];
        atomicAdd(g.ctx_un + bb*512 + d, ssum);
      }
    }
    bar_sync(g.bars + 100 + s, bflag + 100 + s, 256);
  }

  // final ctx_stk[99] (step 99 parity p=1)
  if (tid < 64){
    const int d = tc*64 + tid;
    const float invp = 1.f / cloadf(g.sum_buf + 32 + bb);
    const float cv = cloadf(g.ctx_un + bb*512 + d);
    g.ctx_stk[((size_t)99*32 + bb)*512 + d] = (__bf16)(cv * invp);
  }
}

// ---------------------------------------------------------------------------
extern "C" void kernel_launch(void* const* d_in, const int* in_sizes, int n_in,
                              void* d_out, int out_size, void* d_ws, size_t ws_size,
                              hipStream_t stream){
  (void)in_sizes; (void)n_in; (void)out_size; (void)ws_size;
  const float* enc    = (const float*)d_in[0];
  const int*   labels = (const int*)  d_in[1];
  const int*   seqlen = (const int*)  d_in[2];
  const float* embed  = (const float*)d_in[3];
  const float* W_ih   = (const float*)d_in[4];
  const float* W_hh   = (const float*)d_in[5];
  const float* b_ih   = (const float*)d_in[6];
  const float* b_hh   = (const float*)d_in[7];
  const float* W_s    = (const float*)d_in[8];
  const float* W_enc  = (const float*)d_in[9];
  const float* b_enc  = (const float*)d_in[10];
  const float* v_att  = (const float*)d_in[11];
  const float* W_fert = (const float*)d_in[12];
  const float* W_fb   = (const float*)d_in[13];
  const float* W_ro   = (const float*)d_in[14];
  const float* b_ro   = (const float*)d_in[15];
  const float* W_out  = (const float*)d_in[16];
  const float* b_out  = (const float*)d_in[17];
  float* out = (float*)d_out;

  char* ws = (char*)d_ws;
  size_t off = 0;
  auto alloc = [&](size_t bytes)->char*{
    char* p = ws + off;
    off = (off + bytes + 255) & ~(size_t)255;
    return p;
  };
  __bf16* enc_b16 = (__bf16*)alloc(32000ull*512*2);
  __bf16* enc_ctx = (__bf16*)alloc(32000ull*1024*2);
  __bf16* W_ih_b  = (__bf16*)alloc(4096ull*1152*2);
  __bf16* W_hh_b  = (__bf16*)alloc(4096ull*1024*2);
  __bf16* W_s_b   = (__bf16*)alloc(1024ull*1024*2);
  __bf16* W_enc_b = (__bf16*)alloc(1024ull*512*2);
  __bf16* W_ro_b  = (__bf16*)alloc(1024ull*2176*2);
  __bf16* W_out_b = (__bf16*)alloc(10240ull*512*2);
  __bf16* emb_sbe = (__bf16*)alloc(3200ull*640*2);
  float*  ifert   = (float*)alloc(32000ull*4);
  __bf16* s_stk   = (__bf16*)alloc(3200ull*1024*2);
  __bf16* ctx_stk = (__bf16*)alloc(3200ull*512*2);
  float*  h_st    = (float*)alloc(32768ull*4);
  float*  c_st    = (float*)alloc(32768ull*4);
  __bf16* h_b16   = (__bf16*)alloc(32768ull*2);
  float*  s_t     = (float*)alloc(32768ull*4);
  float*  ctx_un  = (float*)alloc(16384ull*4);
  float*  sum_buf = (float*)alloc(256);
  float*  accum   = (float*)alloc(32000ull*4);
  float*  expe    = (float*)alloc(64000ull*4);
  __bf16* Y       = (__bf16*)alloc(3200ull*512*2);
  unsigned* bars  = (unsigned*)alloc(8192ull*4);

  auto conv = [&](const float* s, __bf16* d, int n){
    int n4 = n/4;
    f32_to_bf16_k<<<(n4+255)/256, 256, 0, stream>>>(s, d, n4);
  };
  conv(enc,   enc_b16, 32000*512);
  conv(W_ih,  W_ih_b,  4096*1152);
  conv(W_hh,  W_hh_b,  4096*1024);
  conv(W_s,   W_s_b,   1024*1024);
  conv(W_enc, W_enc_b, 1024*512);
  conv(W_ro,  W_ro_b,  1024*2176);
  conv(W_out, W_out_b, 10240*512);

  emb_gather_k<<<(256000+255)/256, 256, 0, stream>>>(embed, labels, emb_sbe);
  fert_k<<<8000, 256, 0, stream>>>(enc, W_fert, ifert);
  init_k<<<250, 256, 0, stream>>>(h_st, c_st, h_b16, ctx_un, accum, expe, sum_buf, bars);

  gemm_bt<0><<<dim3(500,16), 256, 0, stream>>>(enc_b16, nullptr, nullptr, W_enc_b,
        b_enc, nullptr, enc_ctx, 32000, 1024, 512);

  DecArgs da;
  da.b_ih = b_ih; da.b_hh = b_hh; da.v_att = v_att; da.W_fb = W_fb;
  da.seqlen = seqlen; da.inv_fert = ifert;
  da.emb_sbe = emb_sbe; da.W_ih_b = W_ih_b; da.W_hh_b = W_hh_b; da.W_s_b = W_s_b;
  da.enc_ctx = enc_ctx; da.enc_b16 = enc_b16;
  da.h_st = h_st; da.c_st = c_st; da.h_b16 = h_b16;
  da.s_t = s_t; da.ctx_un = ctx_un; da.sum_buf = sum_buf;
  da.accum = accum; da.expe = expe;
  da.s_stk = s_stk; da.ctx_stk = ctx_stk;
  da.bars = bars;
  void* kargs[] = { &da };
  hipLaunchCooperativeKernel(reinterpret_cast<void*>(decoder_kernel),
                             dim3(256), dim3(512), kargs, 0, stream);

  gemm_bt<1><<<dim3(50,16), 256, 0, stream>>>(s_stk, emb_sbe, ctx_stk, W_ro_b,
        b_ro, nullptr, Y, 3200, 1024, 2176);
  gemm_bt<2><<<dim3(50,160), 256, 0, stream>>>(Y, nullptr, nullptr, W_out_b,
        b_out, out, nullptr, 3200, 10240, 512);
}